// Round 5
// baseline (545.265 us; speedup 1.0000x reference)
//
#include <hip/hip_runtime.h>
#include <stdint.h>

// MultiHeadedAttentionSANM: B=8,T=1024,F=1024,H=16,Dk=64,KERNEL=11
// Pipeline: cvt->bf16 | GEMM1 qkv (v written transposed) | maskbits+ktT | fsmn->d_out |
//           attn v4 (swapped-QK^T + swapped-PV, 16q/wave, TLP latency hiding) | GEMM2(+bias+fsmn)
// ws layout (bytes): hsb[0,16M) wqkvb[16M,22M) woutb[22M,24M) q[24M,40M) k[40M,56M)
//                    vt[56M,72M) ctx[72M,88M)
// hsb region dead after GEMM1; mbits (1KB @ +0) and ktT (45KB @ +4096) reuse it.
// total ws needed = 92,274,688 bytes

typedef uint16_t u16;
typedef float f32x4 __attribute__((ext_vector_type(4)));
typedef __bf16 bf16x8 __attribute__((ext_vector_type(8)));
typedef __bf16 bf16x2 __attribute__((ext_vector_type(2)));
typedef u16 u16x8 __attribute__((ext_vector_type(8)));
typedef u16 u16x4 __attribute__((ext_vector_type(4)));
typedef short s16x4 __attribute__((ext_vector_type(4)));

__device__ __forceinline__ u16 f2bf(float f) {
    union { float f; uint32_t u; } c; c.f = f;
    uint32_t u = c.u;
    return (u16)((u + 0x7fffu + ((u >> 16) & 1u)) >> 16);
}
__device__ __forceinline__ float bf2f(u16 h) {
    union { uint32_t u; float f; } c; c.u = ((uint32_t)h) << 16;
    return c.f;
}
__device__ __forceinline__ uint32_t pack_bf16(float a, float b) {
    bf16x2 t; t[0] = (__bf16)a; t[1] = (__bf16)b;
    union { bf16x2 v; uint32_t u; } c; c.v = t; return c.u;
}

// ---------------- fp32 -> bf16 convert ----------------
__global__ __launch_bounds__(256) void cvt_f32_bf16(const float* __restrict__ src,
                                                    u16* __restrict__ dst, int n) {
    int i = (blockIdx.x * 256 + threadIdx.x) * 4;
    if (i >= n) return;
    float4 v = *reinterpret_cast<const float4*>(src + i);
    ushort4 o;
    o.x = f2bf(v.x); o.y = f2bf(v.y); o.z = f2bf(v.z); o.w = f2bf(v.w);
    *reinterpret_cast<ushort4*>(dst + i) = o;
}

// ---------------- mask -> bitmask (8 batches x 32 u32) ----------------
__global__ void maskbits_kernel(const int* __restrict__ mask, uint32_t* __restrict__ mb) {
    int i = threadIdx.x;           // 0..255
    int b = i >> 5, c = i & 31;
    uint32_t u = 0;
    for (int j = 0; j < 32; ++j)
        u |= (mask[(b << 10) + c * 32 + j] ? 1u : 0u) << j;
    mb[i] = u;
}

// ---------------- fsmn kernel transpose [1024][11] -> [11][1024] ----------------
__global__ __launch_bounds__(256) void fsmn_kt(const float* __restrict__ fk,
                                               float* __restrict__ kt) {
    int idx = blockIdx.x * 256 + threadIdx.x;
    if (idx < 11 * 1024) {
        int j = idx >> 10, c = idx & 1023;
        kt[idx] = fk[c * 11 + j];
    }
}

// ---------------- 128x128 bf16 MFMA GEMM, B given as [N,K] (B^T form) ----------------
template<int MODE>
__global__ __launch_bounds__(256) void gemm128(
    const u16* __restrict__ A, const u16* __restrict__ Bw, int M, int N, int K,
    int ntiles_n, const float* __restrict__ bias,
    u16* __restrict__ qo, u16* __restrict__ ko, u16* __restrict__ vo,
    float* __restrict__ out)
{
    __shared__ u16 As[128 * 32];
    __shared__ u16 Bs[128 * 32];
    const int t = threadIdx.x;
    const int lane = t & 63;
    const int wave = t >> 6;
    const int wr = wave >> 1, wc = wave & 1;
    const int lr = lane & 15, lq = lane >> 4;
    // bijective XCD swizzle (grid % 8 == 0 for both call sites)
    const int nwg = gridDim.x;
    const int cpx = nwg >> 3;
    const int bid = (blockIdx.x & 7) * cpx + (blockIdx.x >> 3);
    const int mt = bid / ntiles_n;
    const int nt = bid % ntiles_n;
    const int m0 = mt * 128, n0 = nt * 128;

    const u16* ag = A + (size_t)m0 * K;
    const u16* bg = Bw + (size_t)n0 * K;

    f32x4 acc[4][4];
#pragma unroll
    for (int i = 0; i < 4; ++i)
#pragma unroll
        for (int j = 0; j < 4; ++j) acc[i][j] = (f32x4){0.f, 0.f, 0.f, 0.f};

    for (int k0 = 0; k0 < K; k0 += 32) {
#pragma unroll
        for (int i = 0; i < 2; ++i) {
            int c = i * 256 + t;
            const u16* gA = ag + (size_t)(c >> 2) * K + k0 + (c & 3) * 8;
            const u16* gB = bg + (size_t)(c >> 2) * K + k0 + (c & 3) * 8;
            __builtin_amdgcn_global_load_lds(
                (const __attribute__((address_space(1))) void*)gA,
                (__attribute__((address_space(3))) void*)(As + i * 2048 + wave * 512),
                16, 0, 0);
            __builtin_amdgcn_global_load_lds(
                (const __attribute__((address_space(1))) void*)gB,
                (__attribute__((address_space(3))) void*)(Bs + i * 2048 + wave * 512),
                16, 0, 0);
        }
        __syncthreads();
        bf16x8 af[4], bf[4];
#pragma unroll
        for (int m = 0; m < 4; ++m)
            af[m] = *reinterpret_cast<const bf16x8*>(As + (wr * 64 + m * 16 + lr) * 32 + lq * 8);
#pragma unroll
        for (int n = 0; n < 4; ++n)
            bf[n] = *reinterpret_cast<const bf16x8*>(Bs + (wc * 64 + n * 16 + lr) * 32 + lq * 8);
#pragma unroll
        for (int m = 0; m < 4; ++m)
#pragma unroll
            for (int n = 0; n < 4; ++n)
                acc[m][n] = __builtin_amdgcn_mfma_f32_16x16x32_bf16(af[m], bf[n], acc[m][n], 0, 0, 0);
        __syncthreads();
    }

#pragma unroll
    for (int m = 0; m < 4; ++m) {
        int row = m0 + wr * 64 + m * 16 + lq * 4;
#pragma unroll
        for (int n = 0; n < 4; ++n) {
            int col = n0 + wc * 64 + n * 16 + lr;
            float bv = bias[col];
#pragma unroll
            for (int r = 0; r < 4; ++r) {
                float val = acc[m][n][r] + bv;
                int rr = row + r;
                if (MODE == 0) {
                    int part = col >> 10;
                    int cc = col & 1023;
                    int h = cc >> 6, d = cc & 63;
                    int b = rr >> 10, tt = rr & 1023;
                    size_t bh = (size_t)(b * 16 + h);
                    if (part == 0)      qo[((bh << 10) + tt) * 64 + d] = f2bf(val * 0.125f);
                    else if (part == 1) ko[((bh << 10) + tt) * 64 + d] = f2bf(val);
                    else                vo[(bh << 16) + (size_t)d * 1024 + tt] = f2bf(val);
                } else {
                    size_t o = (size_t)rr * N + col;
                    out[o] += val;
                }
            }
        }
    }
}

// ---------------- FSMN v3: LDS-transpose, reads vt coalesced, writes d_out coalesced ----
__global__ __launch_bounds__(256) void fsmn_v3(const u16* __restrict__ vt,
                                               const int* __restrict__ mask,
                                               const float* __restrict__ kt,
                                               float* __restrict__ out)
{
    __shared__ float vs[64][147];
    __shared__ float ms[144];
    const int tid = threadIdx.x;
    const int tc = blockIdx.x & 7;
    const int bh = blockIdx.x >> 3;
    const int b = bh >> 4, h = bh & 15;
    const int t0 = tc * 128;
    const u16* vrow = vt + ((size_t)bh << 16);
    const int* mrow = mask + (b << 10);

    if (tid < 144) {
        int tt = t0 - 8 + tid;
        ms[tid] = (tt >= 0 && tt < 1024) ? (float)mrow[tt] : 0.f;
    }
    const int sd = tid >> 2;
    const int ci0 = tid & 3;
#pragma unroll
    for (int it = 0; it < 5; ++it) {
        int ci = ci0 + it * 4;
        if (ci < 18) {
            int tbase = t0 - 8 + ci * 8;
            if (tbase >= 0 && tbase < 1024) {
                u16x8 v8 = *reinterpret_cast<const u16x8*>(vrow + (size_t)sd * 1024 + tbase);
#pragma unroll
                for (int j = 0; j < 8; ++j)
                    vs[sd][ci * 8 + j] = bf2f((u16)v8[j]) * (float)mrow[tbase + j];
            } else {
#pragma unroll
                for (int j = 0; j < 8; ++j) vs[sd][ci * 8 + j] = 0.f;
            }
        }
    }
    __syncthreads();

    const int dd = tid & 63;
    const int tg = tid >> 6;
    const int c = h * 64 + dd;
    float kc[11];
#pragma unroll
    for (int j = 0; j < 11; ++j) kc[j] = kt[j * 1024 + c];

    const int tl0 = tg * 32;
    float w[11];
#pragma unroll
    for (int j = 0; j < 11; ++j) w[j] = vs[dd][3 + tl0 + j];
    float* orow = out + ((size_t)(b * 1024 + t0 + tl0)) * 1024 + c;
#pragma unroll 4
    for (int s = 0; s < 32; ++s) {
        float acc = 0.f;
#pragma unroll
        for (int j = 0; j < 11; ++j) acc += kc[j] * w[j];
        float mf = ms[8 + tl0 + s];
        orow[(size_t)s * 1024] = (acc + w[5]) * mf;
#pragma unroll
        for (int j = 0; j < 10; ++j) w[j] = w[j + 1];
        w[10] = vs[dd][3 + tl0 + s + 11];
    }
}

// ---------------- attention v4: 16 q-rows/wave, occupancy-driven latency hiding ----------
// grid = 2048: bh = bid&127 (XCD-local), qc = bid>>7 (16 chunks of 64 rows)
// block = 4 waves; wave w owns q rows q0 = qc*64 + w*16.
// S^T = mfma_16x16x32(A=K, B=Q^T): lane holds q=lane&15, key rows 4*lq+r per 16-tile
// O^T = mfma_16x16x16(A=V^T frag, B=P^T frag == S^T layout, no cross-lane ops)
__global__ __launch_bounds__(256, 6) void attn_v4(const u16* __restrict__ qg,
                                                  const u16* __restrict__ kg,
                                                  const u16* __restrict__ vtg,
                                                  const uint32_t* __restrict__ mbits,
                                                  u16* __restrict__ ctx)
{
    const int t = threadIdx.x;
    const int lane = t & 63;
    const int w = t >> 6;
    const int lr = lane & 15, lq = lane >> 4;
    const int bh = blockIdx.x & 127;      // fast-varying: same-bh blocks on same XCD
    const int qc = blockIdx.x >> 7;
    const int b = bh >> 4, h = bh & 15;
    const size_t base = (size_t)bh << 16;
    const u16* kb = kg + base;
    const u16* vb = vtg + base;           // [64][1024]
    const int q0 = qc * 64 + w * 16;

    // Q fragments (B-operand of QK^T): lane holds Q[q=lr][32*kk+8*lq+e]
    bf16x8 qf[2];
#pragma unroll
    for (int kk = 0; kk < 2; ++kk)
        qf[kk] = *reinterpret_cast<const bf16x8*>(
            qg + base + (size_t)(q0 + lr) * 64 + kk * 32 + lq * 8);

    f32x4 oacc[4];                        // [dt]; D[d'=4lq+r][q=lr]
    float m_ = -1e30f, l_ = 0.f;
#pragma unroll
    for (int dt = 0; dt < 4; ++dt) oacc[dt] = (f32x4){0.f, 0.f, 0.f, 0.f};

    const uint32_t* mrow = mbits + b * 32;

    for (int it = 0; it < 32; ++it) {
        // operand loads (compiler hoists/schedules; TLP hides L2 latency)
        bf16x8 kf[2][2];                  // K[key=it*32+kt*16+lr][32kk+8lq+e]
        s16x4  vf[2][4];                  // V^T[d=dt*16+lr][k=it*32+16ks+4lq+e]
#pragma unroll
        for (int kt = 0; kt < 2; ++kt)
#pragma unroll
            for (int kk = 0; kk < 2; ++kk)
                kf[kt][kk] = *reinterpret_cast<const bf16x8*>(
                    kb + (size_t)(it * 32 + kt * 16 + lr) * 64 + kk * 32 + lq * 8);
#pragma unroll
        for (int ks = 0; ks < 2; ++ks)
#pragma unroll
            for (int dt = 0; dt < 4; ++dt)
                vf[ks][dt] = *reinterpret_cast<const s16x4*>(
                    vb + (size_t)(dt * 16 + lr) * 1024 + it * 32 + ks * 16 + lq * 4);

        const uint32_t mbit = mrow[it];
        f32x4 ma[2];
#pragma unroll
        for (int kt = 0; kt < 2; ++kt)
#pragma unroll
            for (int r = 0; r < 4; ++r)
                ma[kt][r] = ((mbit >> (kt * 16 + lq * 4 + r)) & 1u) ? 0.f : -3e38f;

        f32x4 s0 = (f32x4){0.f, 0.f, 0.f, 0.f};
        f32x4 s1 = (f32x4){0.f, 0.f, 0.f, 0.f};
        s0 = __builtin_amdgcn_mfma_f32_16x16x32_bf16(kf[0][0], qf[0], s0, 0, 0, 0);
        s0 = __builtin_amdgcn_mfma_f32_16x16x32_bf16(kf[0][1], qf[1], s0, 0, 0, 0);
        s1 = __builtin_amdgcn_mfma_f32_16x16x32_bf16(kf[1][0], qf[0], s1, 0, 0, 0);
        s1 = __builtin_amdgcn_mfma_f32_16x16x32_bf16(kf[1][1], qf[1], s1, 0, 0, 0);
        s0 += ma[0]; s1 += ma[1];
        float mx = fmaxf(fmaxf(fmaxf(s0[0], s0[1]), fmaxf(s0[2], s0[3])),
                         fmaxf(fmaxf(s1[0], s1[1]), fmaxf(s1[2], s1[3])));
        mx = fmaxf(mx, __shfl_xor(mx, 16, 64));
        mx = fmaxf(mx, __shfl_xor(mx, 32, 64));
        float mn = fmaxf(m_, mx);
        float al = __expf(m_ - mn);
        m_ = mn;
        float p0 = __expf(s0[0] - mn), p1 = __expf(s0[1] - mn);
        float p2 = __expf(s0[2] - mn), p3 = __expf(s0[3] - mn);
        float p4 = __expf(s1[0] - mn), p5 = __expf(s1[1] - mn);
        float p6 = __expf(s1[2] - mn), p7 = __expf(s1[3] - mn);
        float rs = ((p0 + p1) + (p2 + p3)) + ((p4 + p5) + (p6 + p7));
        rs += __shfl_xor(rs, 16, 64);
        rs += __shfl_xor(rs, 32, 64);
        l_ = l_ * al + rs;

        union { uint32_t u[2]; s16x4 v; } pa0, pa1;
        pa0.u[0] = pack_bf16(p0, p1); pa0.u[1] = pack_bf16(p2, p3);
        pa1.u[0] = pack_bf16(p4, p5); pa1.u[1] = pack_bf16(p6, p7);

        // rescale (alpha lane-local: output cols = q = lane&15), then PV
#pragma unroll
        for (int dt = 0; dt < 4; ++dt) {
            f32x4 o = oacc[dt];
            o[0] *= al; o[1] *= al; o[2] *= al; o[3] *= al;
            o = __builtin_amdgcn_mfma_f32_16x16x16bf16_1k(vf[0][dt], pa0.v, o, 0, 0, 0);
            o = __builtin_amdgcn_mfma_f32_16x16x16bf16_1k(vf[1][dt], pa1.v, o, 0, 0, 0);
            oacc[dt] = o;
        }
    }

    // epilogue: lane holds O[d'=dt*16+4lq+r][q=lr]; 8B stores
    {
        float li = 1.f / l_;
        int trow = q0 + lr;
        u16* crow = ctx + ((size_t)(b << 10) + trow) * 1024 + h * 64;
#pragma unroll
        for (int dt = 0; dt < 4; ++dt) {
            f32x4 o = oacc[dt];
            u16x4 pkv;
            pkv[0] = f2bf(o[0] * li); pkv[1] = f2bf(o[1] * li);
            pkv[2] = f2bf(o[2] * li); pkv[3] = f2bf(o[3] * li);
            *reinterpret_cast<u16x4*>(crow + dt * 16 + lq * 4) = pkv;
        }
    }
}

extern "C" void kernel_launch(void* const* d_in, const int* in_sizes, int n_in,
                              void* d_out, int out_size, void* d_ws, size_t ws_size,
                              hipStream_t stream)
{
    (void)in_sizes; (void)n_in; (void)out_size; (void)ws_size;
    const float* hs   = (const float*)d_in[0];
    const int*   mask = (const int*)d_in[1];
    const float* Wqkv = (const float*)d_in[2];
    const float* bqkv = (const float*)d_in[3];
    const float* Wout = (const float*)d_in[4];
    const float* bout = (const float*)d_in[5];
    const float* fk   = (const float*)d_in[6];
    float* out = (float*)d_out;

    char* ws = (char*)d_ws;
    u16* hsb   = (u16*)(ws);
    u16* wqkvb = (u16*)(ws + 16777216);
    u16* woutb = (u16*)(ws + 23068672);
    u16* qb    = (u16*)(ws + 25165824);      // [B,H,T,64]
    u16* kb    = (u16*)(ws + 41943040);      // [B,H,T,64]
    u16* vtb   = (u16*)(ws + 58720256);      // [B,H,64,T]
    u16* ctxb  = (u16*)(ws + 75497472);      // [B,T,1024]
    uint32_t* mbits = (uint32_t*)ws;
    float* ktT = (float*)(ws + 4096);

    cvt_f32_bf16<<<8192, 256, 0, stream>>>(hs,   hsb,   8388608);
    cvt_f32_bf16<<<3072, 256, 0, stream>>>(Wqkv, wqkvb, 3145728);
    cvt_f32_bf16<<<1024, 256, 0, stream>>>(Wout, woutb, 1048576);

    gemm128<0><<<64 * 24, 256, 0, stream>>>(hsb, wqkvb, 8192, 3072, 1024, 24,
                                            bqkv, qb, kb, vtb, nullptr);
    maskbits_kernel<<<1, 256, 0, stream>>>(mask, mbits);
    fsmn_kt<<<44, 256, 0, stream>>>(fk, ktT);
    fsmn_v3<<<1024, 256, 0, stream>>>(vtb, mask, ktT, out);
    attn_v4<<<2048, 256, 0, stream>>>(qb, kb, vtb, mbits, ctxb);
    gemm128<1><<<64 * 8, 256, 0, stream>>>(ctxb, woutb, 8192, 1024, 1024, 8,
                                           bout, nullptr, nullptr, nullptr, out);
}

// Round 6
// 250.662 us; speedup vs baseline: 2.1753x; 2.1753x over previous
//
#include <hip/hip_runtime.h>
#include <stdint.h>

// MultiHeadedAttentionSANM: B=8,T=1024,F=1024,H=16,Dk=64,KERNEL=11
// Pipeline: cvt->bf16 | GEMM1 qkv (v written transposed) | maskbits+ktT | fsmn->d_out |
//           attn v5 (LDS-staged K/V double-buffer, swapped-QK^T + swapped-PV) | GEMM2
// ws layout (bytes): hsb[0,16M) wqkvb[16M,22M) woutb[22M,24M) q[24M,40M) k[40M,56M)
//                    vt[56M,72M) ctx[72M,88M)
// hsb region dead after GEMM1; mbits (1KB @ +0) and ktT (45KB @ +4096) reuse it.
// total ws needed = 92,274,688 bytes

typedef uint16_t u16;
typedef float f32x4 __attribute__((ext_vector_type(4)));
typedef __bf16 bf16x8 __attribute__((ext_vector_type(8)));
typedef __bf16 bf16x2 __attribute__((ext_vector_type(2)));
typedef u16 u16x8 __attribute__((ext_vector_type(8)));
typedef u16 u16x4 __attribute__((ext_vector_type(4)));
typedef short s16x4 __attribute__((ext_vector_type(4)));

__device__ __forceinline__ u16 f2bf(float f) {
    union { float f; uint32_t u; } c; c.f = f;
    uint32_t u = c.u;
    return (u16)((u + 0x7fffu + ((u >> 16) & 1u)) >> 16);
}
__device__ __forceinline__ float bf2f(u16 h) {
    union { uint32_t u; float f; } c; c.u = ((uint32_t)h) << 16;
    return c.f;
}
__device__ __forceinline__ uint32_t pack_bf16(float a, float b) {
    bf16x2 t; t[0] = (__bf16)a; t[1] = (__bf16)b;
    union { bf16x2 v; uint32_t u; } c; c.v = t; return c.u;
}

// ---------------- fp32 -> bf16 convert ----------------
__global__ __launch_bounds__(256) void cvt_f32_bf16(const float* __restrict__ src,
                                                    u16* __restrict__ dst, int n) {
    int i = (blockIdx.x * 256 + threadIdx.x) * 4;
    if (i >= n) return;
    float4 v = *reinterpret_cast<const float4*>(src + i);
    ushort4 o;
    o.x = f2bf(v.x); o.y = f2bf(v.y); o.z = f2bf(v.z); o.w = f2bf(v.w);
    *reinterpret_cast<ushort4*>(dst + i) = o;
}

// ---------------- mask -> bitmask (8 batches x 32 u32) ----------------
__global__ void maskbits_kernel(const int* __restrict__ mask, uint32_t* __restrict__ mb) {
    int i = threadIdx.x;           // 0..255
    int b = i >> 5, c = i & 31;
    uint32_t u = 0;
    for (int j = 0; j < 32; ++j)
        u |= (mask[(b << 10) + c * 32 + j] ? 1u : 0u) << j;
    mb[i] = u;
}

// ---------------- fsmn kernel transpose [1024][11] -> [11][1024] ----------------
__global__ __launch_bounds__(256) void fsmn_kt(const float* __restrict__ fk,
                                               float* __restrict__ kt) {
    int idx = blockIdx.x * 256 + threadIdx.x;
    if (idx < 11 * 1024) {
        int j = idx >> 10, c = idx & 1023;
        kt[idx] = fk[c * 11 + j];
    }
}

// ---------------- 128x128 bf16 MFMA GEMM, B given as [N,K] (B^T form) ----------------
template<int MODE>
__global__ __launch_bounds__(256) void gemm128(
    const u16* __restrict__ A, const u16* __restrict__ Bw, int M, int N, int K,
    int ntiles_n, const float* __restrict__ bias,
    u16* __restrict__ qo, u16* __restrict__ ko, u16* __restrict__ vo,
    float* __restrict__ out)
{
    __shared__ u16 As[128 * 32];
    __shared__ u16 Bs[128 * 32];
    const int t = threadIdx.x;
    const int lane = t & 63;
    const int wave = t >> 6;
    const int wr = wave >> 1, wc = wave & 1;
    const int lr = lane & 15, lq = lane >> 4;
    // bijective XCD swizzle (grid % 8 == 0 for both call sites)
    const int nwg = gridDim.x;
    const int cpx = nwg >> 3;
    const int bid = (blockIdx.x & 7) * cpx + (blockIdx.x >> 3);
    const int mt = bid / ntiles_n;
    const int nt = bid % ntiles_n;
    const int m0 = mt * 128, n0 = nt * 128;

    const u16* ag = A + (size_t)m0 * K;
    const u16* bg = Bw + (size_t)n0 * K;

    f32x4 acc[4][4];
#pragma unroll
    for (int i = 0; i < 4; ++i)
#pragma unroll
        for (int j = 0; j < 4; ++j) acc[i][j] = (f32x4){0.f, 0.f, 0.f, 0.f};

    for (int k0 = 0; k0 < K; k0 += 32) {
#pragma unroll
        for (int i = 0; i < 2; ++i) {
            int c = i * 256 + t;
            const u16* gA = ag + (size_t)(c >> 2) * K + k0 + (c & 3) * 8;
            const u16* gB = bg + (size_t)(c >> 2) * K + k0 + (c & 3) * 8;
            __builtin_amdgcn_global_load_lds(
                (const __attribute__((address_space(1))) void*)gA,
                (__attribute__((address_space(3))) void*)(As + i * 2048 + wave * 512),
                16, 0, 0);
            __builtin_amdgcn_global_load_lds(
                (const __attribute__((address_space(1))) void*)gB,
                (__attribute__((address_space(3))) void*)(Bs + i * 2048 + wave * 512),
                16, 0, 0);
        }
        __syncthreads();
        bf16x8 af[4], bf[4];
#pragma unroll
        for (int m = 0; m < 4; ++m)
            af[m] = *reinterpret_cast<const bf16x8*>(As + (wr * 64 + m * 16 + lr) * 32 + lq * 8);
#pragma unroll
        for (int n = 0; n < 4; ++n)
            bf[n] = *reinterpret_cast<const bf16x8*>(Bs + (wc * 64 + n * 16 + lr) * 32 + lq * 8);
#pragma unroll
        for (int m = 0; m < 4; ++m)
#pragma unroll
            for (int n = 0; n < 4; ++n)
                acc[m][n] = __builtin_amdgcn_mfma_f32_16x16x32_bf16(af[m], bf[n], acc[m][n], 0, 0, 0);
        __syncthreads();
    }

#pragma unroll
    for (int m = 0; m < 4; ++m) {
        int row = m0 + wr * 64 + m * 16 + lq * 4;
#pragma unroll
        for (int n = 0; n < 4; ++n) {
            int col = n0 + wc * 64 + n * 16 + lr;
            float bv = bias[col];
#pragma unroll
            for (int r = 0; r < 4; ++r) {
                float val = acc[m][n][r] + bv;
                int rr = row + r;
                if (MODE == 0) {
                    int part = col >> 10;
                    int cc = col & 1023;
                    int h = cc >> 6, d = cc & 63;
                    int b = rr >> 10, tt = rr & 1023;
                    size_t bh = (size_t)(b * 16 + h);
                    if (part == 0)      qo[((bh << 10) + tt) * 64 + d] = f2bf(val * 0.125f);
                    else if (part == 1) ko[((bh << 10) + tt) * 64 + d] = f2bf(val);
                    else                vo[(bh << 16) + (size_t)d * 1024 + tt] = f2bf(val);
                } else {
                    size_t o = (size_t)rr * N + col;
                    out[o] += val;
                }
            }
        }
    }
}

// ---------------- FSMN v3: LDS-transpose, reads vt coalesced, writes d_out coalesced ----
__global__ __launch_bounds__(256) void fsmn_v3(const u16* __restrict__ vt,
                                               const int* __restrict__ mask,
                                               const float* __restrict__ kt,
                                               float* __restrict__ out)
{
    __shared__ float vs[64][147];
    __shared__ float ms[144];
    const int tid = threadIdx.x;
    const int tc = blockIdx.x & 7;
    const int bh = blockIdx.x >> 3;
    const int b = bh >> 4, h = bh & 15;
    const int t0 = tc * 128;
    const u16* vrow = vt + ((size_t)bh << 16);
    const int* mrow = mask + (b << 10);

    if (tid < 144) {
        int tt = t0 - 8 + tid;
        ms[tid] = (tt >= 0 && tt < 1024) ? (float)mrow[tt] : 0.f;
    }
    const int sd = tid >> 2;
    const int ci0 = tid & 3;
#pragma unroll
    for (int it = 0; it < 5; ++it) {
        int ci = ci0 + it * 4;
        if (ci < 18) {
            int tbase = t0 - 8 + ci * 8;
            if (tbase >= 0 && tbase < 1024) {
                u16x8 v8 = *reinterpret_cast<const u16x8*>(vrow + (size_t)sd * 1024 + tbase);
#pragma unroll
                for (int j = 0; j < 8; ++j)
                    vs[sd][ci * 8 + j] = bf2f((u16)v8[j]) * (float)mrow[tbase + j];
            } else {
#pragma unroll
                for (int j = 0; j < 8; ++j) vs[sd][ci * 8 + j] = 0.f;
            }
        }
    }
    __syncthreads();

    const int dd = tid & 63;
    const int tg = tid >> 6;
    const int c = h * 64 + dd;
    float kc[11];
#pragma unroll
    for (int j = 0; j < 11; ++j) kc[j] = kt[j * 1024 + c];

    const int tl0 = tg * 32;
    float w[11];
#pragma unroll
    for (int j = 0; j < 11; ++j) w[j] = vs[dd][3 + tl0 + j];
    float* orow = out + ((size_t)(b * 1024 + t0 + tl0)) * 1024 + c;
#pragma unroll 4
    for (int s = 0; s < 32; ++s) {
        float acc = 0.f;
#pragma unroll
        for (int j = 0; j < 11; ++j) acc += kc[j] * w[j];
        float mf = ms[8 + tl0 + s];
        orow[(size_t)s * 1024] = (acc + w[5]) * mf;
#pragma unroll
        for (int j = 0; j < 10; ++j) w[j] = w[j + 1];
        w[10] = vs[dd][3 + tl0 + s + 11];
    }
}

// ---------------- attention v5: LDS-staged K/V (double-buffered), swapped QK^T + PV ----
// grid = 1024: bh = bid&127 (XCD-local), qc = bid>>7; block = 4 waves x 32 q-rows.
// K tile [64 key][64 d], V^T tile [64 d][64 key], XOR-swizzled (g ^= row&7 on 16B granules)
// via pre-swizzled global source (linear LDS dest, global_load_lds).
// S^T = mfma_16x16x32(A=K, B=Q^T); O^T = mfma_16x16x16(A=V^T, B=P^T == S^T layout).
__global__ __launch_bounds__(256) void attn_v5(const u16* __restrict__ qg,
                                               const u16* __restrict__ kg,
                                               const u16* __restrict__ vtg,
                                               const uint32_t* __restrict__ mbits,
                                               u16* __restrict__ ctx)
{
    __shared__ u16 K_s[2][64 * 64];
    __shared__ u16 V_s[2][64 * 64];
    const int t = threadIdx.x;
    const int lane = t & 63;
    const int w = t >> 6;
    const int lr = lane & 15, lq = lane >> 4;
    const int bh = blockIdx.x & 127;      // fast-varying: same-bh blocks on same XCD
    const int qc = blockIdx.x >> 7;
    const int b = bh >> 4, h = bh & 15;
    const size_t base = (size_t)bh << 16;
    const u16* kb = kg + base;            // [1024 key][64 d]
    const u16* vb = vtg + base;           // [64 d][1024 key]
    const int q0 = qc * 128 + w * 32;

    // Q fragments (B-operand of QK^T): lane holds Q[q=lr][32*kk+8*lq+e]
    bf16x8 qf[2][2];
#pragma unroll
    for (int qt = 0; qt < 2; ++qt)
#pragma unroll
        for (int kk = 0; kk < 2; ++kk)
            qf[qt][kk] = *reinterpret_cast<const bf16x8*>(
                qg + base + (size_t)(q0 + qt * 16 + lr) * 64 + kk * 32 + lq * 8);

    f32x4 oacc[2][4];                     // [qt][dt]; D[d'=4lq+r][q=lr]
    float m_[2] = {-1e30f, -1e30f}, l_[2] = {0.f, 0.f};
#pragma unroll
    for (int qt = 0; qt < 2; ++qt)
#pragma unroll
        for (int dt = 0; dt < 4; ++dt) oacc[qt][dt] = (f32x4){0.f, 0.f, 0.f, 0.f};

    const uint32_t* mrow = mbits + b * 32;

    // stage one 64-key tile (K + V^T) into buffer bufi; pre-swizzled global source
    auto stage = [&](int bufi, int tile) {
        const int k0s = tile * 64;
#pragma unroll
        for (int rd = 0; rd < 2; ++rd) {
            int ch = rd * 256 + w * 64 + lane;     // chunk id 0..511
            int row = ch >> 3, c7 = ch & 7;
            int sc = (c7 ^ (row & 7)) * 8;         // swizzled source granule (u16 units)
            const u16* srcK = kb + (size_t)(k0s + row) * 64 + sc;
            const u16* srcV = vb + (size_t)row * 1024 + k0s + sc;
            u16* dK = &K_s[bufi][(size_t)(rd * 256 + w * 64) * 8];
            u16* dV = &V_s[bufi][(size_t)(rd * 256 + w * 64) * 8];
            __builtin_amdgcn_global_load_lds(
                (const __attribute__((address_space(1))) void*)srcK,
                (__attribute__((address_space(3))) void*)dK, 16, 0, 0);
            __builtin_amdgcn_global_load_lds(
                (const __attribute__((address_space(1))) void*)srcV,
                (__attribute__((address_space(3))) void*)dV, 16, 0, 0);
        }
    };

    int cur = 0;
    stage(0, 0);
    asm volatile("s_waitcnt vmcnt(0)");
    __syncthreads();

    for (int it = 0; it < 16; ++it) {
        if (it < 15) stage(cur ^ 1, it + 1);   // loads in flight across compute

        // --- K fragments (swizzled ds_read, 2-way conflict = free) ---
        const u16* Kb = K_s[cur];
        bf16x8 kf[4][2];
#pragma unroll
        for (int kt = 0; kt < 4; ++kt) {
            int row = kt * 16 + lr;
#pragma unroll
            for (int kk = 0; kk < 2; ++kk) {
                int g = (kk * 4 + lq) ^ (row & 7);
                kf[kt][kk] = *reinterpret_cast<const bf16x8*>(Kb + row * 64 + g * 8);
            }
        }

        // --- QK^T for both q-subtiles ---
        f32x4 s[2][4];
#pragma unroll
        for (int qt = 0; qt < 2; ++qt)
#pragma unroll
            for (int kt = 0; kt < 4; ++kt) {
                f32x4 acc = (f32x4){0.f, 0.f, 0.f, 0.f};
                acc = __builtin_amdgcn_mfma_f32_16x16x32_bf16(kf[kt][0], qf[qt][0], acc, 0, 0, 0);
                acc = __builtin_amdgcn_mfma_f32_16x16x32_bf16(kf[kt][1], qf[qt][1], acc, 0, 0, 0);
                s[qt][kt] = acc;
            }

        // --- mask ---
        const uint32_t mw0 = mrow[it * 2], mw1 = mrow[it * 2 + 1];
        f32x4 ma[4];
#pragma unroll
        for (int kt = 0; kt < 4; ++kt) {
            uint32_t mw = (kt < 2) ? mw0 : mw1;
#pragma unroll
            for (int r = 0; r < 4; ++r)
                ma[kt][r] = ((mw >> ((kt & 1) * 16 + lq * 4 + r)) & 1u) ? 0.f : -3e38f;
        }

        // --- V^T fragments ---
        const u16* Vb = V_s[cur];
        s16x4 vf[4][4];
#pragma unroll
        for (int ks = 0; ks < 4; ++ks)
#pragma unroll
            for (int dt = 0; dt < 4; ++dt) {
                int row = dt * 16 + lr;
                int g = (ks * 2 + (lq >> 1)) ^ (row & 7);
                vf[ks][dt] = *reinterpret_cast<const s16x4*>(Vb + row * 64 + g * 8 + (lq & 1) * 4);
            }

        // --- softmax + PV per q-subtile ---
#pragma unroll
        for (int qt = 0; qt < 2; ++qt) {
#pragma unroll
            for (int kt = 0; kt < 4; ++kt) s[qt][kt] += ma[kt];
            float mx = fmaxf(fmaxf(fmaxf(s[qt][0][0], s[qt][0][1]), fmaxf(s[qt][0][2], s[qt][0][3])),
                             fmaxf(fmaxf(s[qt][1][0], s[qt][1][1]), fmaxf(s[qt][1][2], s[qt][1][3])));
            float mx2 = fmaxf(fmaxf(fmaxf(s[qt][2][0], s[qt][2][1]), fmaxf(s[qt][2][2], s[qt][2][3])),
                              fmaxf(fmaxf(s[qt][3][0], s[qt][3][1]), fmaxf(s[qt][3][2], s[qt][3][3])));
            mx = fmaxf(mx, mx2);
            mx = fmaxf(mx, __shfl_xor(mx, 16, 64));
            mx = fmaxf(mx, __shfl_xor(mx, 32, 64));
            float mn = fmaxf(m_[qt], mx);
            float al = __expf(m_[qt] - mn);
            m_[qt] = mn;

            float p[4][4], rs = 0.f;
#pragma unroll
            for (int kt = 0; kt < 4; ++kt)
#pragma unroll
                for (int r = 0; r < 4; ++r) {
                    p[kt][r] = __expf(s[qt][kt][r] - mn);
                    rs += p[kt][r];
                }
            rs += __shfl_xor(rs, 16, 64);
            rs += __shfl_xor(rs, 32, 64);
            l_[qt] = l_[qt] * al + rs;

            union { uint32_t u[2]; s16x4 v; } pa[4];
#pragma unroll
            for (int kt = 0; kt < 4; ++kt) {
                pa[kt].u[0] = pack_bf16(p[kt][0], p[kt][1]);
                pa[kt].u[1] = pack_bf16(p[kt][2], p[kt][3]);
            }

#pragma unroll
            for (int dt = 0; dt < 4; ++dt) {
                f32x4 o = oacc[qt][dt];
                o[0] *= al; o[1] *= al; o[2] *= al; o[3] *= al;
#pragma unroll
                for (int kt = 0; kt < 4; ++kt)
                    o = __builtin_amdgcn_mfma_f32_16x16x16bf16_1k(vf[kt][dt], pa[kt].v, o, 0, 0, 0);
                oacc[qt][dt] = o;
            }
        }

        asm volatile("s_waitcnt vmcnt(0)" ::: "memory");
        __syncthreads();
        cur ^= 1;
    }

    // epilogue: lane holds O[d'=dt*16+4lq+r][q=lr]; 8B stores
#pragma unroll
    for (int qt = 0; qt < 2; ++qt) {
        float li = 1.f / l_[qt];
        int trow = q0 + qt * 16 + lr;
        u16* crow = ctx + ((size_t)(b << 10) + trow) * 1024 + h * 64;
#pragma unroll
        for (int dt = 0; dt < 4; ++dt) {
            f32x4 o = oacc[qt][dt];
            u16x4 pkv;
            pkv[0] = f2bf(o[0] * li); pkv[1] = f2bf(o[1] * li);
            pkv[2] = f2bf(o[2] * li); pkv[3] = f2bf(o[3] * li);
            *reinterpret_cast<u16x4*>(crow + dt * 16 + lq * 4) = pkv;
        }
    }
}

extern "C" void kernel_launch(void* const* d_in, const int* in_sizes, int n_in,
                              void* d_out, int out_size, void* d_ws, size_t ws_size,
                              hipStream_t stream)
{
    (void)in_sizes; (void)n_in; (void)out_size; (void)ws_size;
    const float* hs   = (const float*)d_in[0];
    const int*   mask = (const int*)d_in[1];
    const float* Wqkv = (const float*)d_in[2];
    const float* bqkv = (const float*)d_in[3];
    const float* Wout = (const float*)d_in[4];
    const float* bout = (const float*)d_in[5];
    const float* fk   = (const float*)d_in[6];
    float* out = (float*)d_out;

    char* ws = (char*)d_ws;
    u16* hsb   = (u16*)(ws);
    u16* wqkvb = (u16*)(ws + 16777216);
    u16* woutb = (u16*)(ws + 23068672);
    u16* qb    = (u16*)(ws + 25165824);      // [B,H,T,64]
    u16* kb    = (u16*)(ws + 41943040);      // [B,H,T,64]
    u16* vtb   = (u16*)(ws + 58720256);      // [B,H,64,T]
    u16* ctxb  = (u16*)(ws + 75497472);      // [B,T,1024]
    uint32_t* mbits = (uint32_t*)ws;
    float* ktT = (float*)(ws + 4096);

    cvt_f32_bf16<<<8192, 256, 0, stream>>>(hs,   hsb,   8388608);
    cvt_f32_bf16<<<3072, 256, 0, stream>>>(Wqkv, wqkvb, 3145728);
    cvt_f32_bf16<<<1024, 256, 0, stream>>>(Wout, woutb, 1048576);

    gemm128<0><<<64 * 24, 256, 0, stream>>>(hsb, wqkvb, 8192, 3072, 1024, 24,
                                            bqkv, qb, kb, vtb, nullptr);
    maskbits_kernel<<<1, 256, 0, stream>>>(mask, mbits);
    fsmn_kt<<<44, 256, 0, stream>>>(fk, ktT);
    fsmn_v3<<<1024, 256, 0, stream>>>(vtb, mask, ktT, out);
    attn_v5<<<1024, 256, 0, stream>>>(qb, kb, vtb, mbits, ctxb);
    gemm128<1><<<64 * 8, 256, 0, stream>>>(ctxb, woutb, 8192, 1024, 1024, 8,
                                           bout, nullptr, nullptr, nullptr, out);
}